// Round 1
// baseline (376.764 us; speedup 1.0000x reference)
//
#include <hip/hip_runtime.h>
#include <hip/hip_bf16.h>
#include <math.h>

// Problem constants
#define TT   4096     // T
#define BB   16       // B
#define NTOK 65536    // B*T
#define CIN  512      // IN_FEATS
#define EF   256      // EMBED_FEATS
#define NE   1024     // NUM_EMBED

typedef __attribute__((ext_vector_type(8))) short bf16x8;
typedef __attribute__((ext_vector_type(4))) float f32x4;

static __device__ __forceinline__ unsigned short f2bf(float f) {
  unsigned int u = __float_as_uint(f);
  u += 0x7fffu + ((u >> 16) & 1u);          // RNE
  return (unsigned short)(u >> 16);
}
static __device__ __forceinline__ float bf2f(unsigned short h) {
  return __uint_as_float(((unsigned int)h) << 16);
}

// async global->LDS, 16B per lane; LDS dest is wave-uniform base + lane*16
#define GLL(gsrc, ldst) \
  __builtin_amdgcn_global_load_lds((const __attribute__((address_space(1))) void*)(gsrc), \
                                   (__attribute__((address_space(3))) void*)(ldst), 16, 0, 0)

// ---------------------------------------------------------------------------
// K1: transpose+convert inputs [B][CIN][TT] f32  ->  Abf [NTOK][CIN] bf16
// ---------------------------------------------------------------------------
__global__ __launch_bounds__(256) void k_transpose(const float* __restrict__ in,
                                                   unsigned short* __restrict__ Abf) {
  __shared__ float sm[64][65];
  int t0 = blockIdx.x * 64;
  int c0 = blockIdx.y * 64;
  int bb = blockIdx.z;
  int tid = threadIdx.x;
  int tl = tid & 63, cg = tid >> 6;   // load phase: lanes over t (coalesced 256B)
  const float* src = in + ((size_t)bb * CIN + c0) * TT + t0;
#pragma unroll
  for (int i = 0; i < 16; ++i) {
    int cl = cg * 16 + i;
    sm[tl][cl] = src[(size_t)cl * TT + tl];
  }
  __syncthreads();
  int trow = tid >> 2, cpart = tid & 3;  // write phase: 4 threads per token row
  unsigned short tmp[16];
#pragma unroll
  for (int j = 0; j < 16; ++j) tmp[j] = f2bf(sm[trow][cpart * 16 + j]);
  unsigned short* dst = Abf + (size_t)(bb * TT + t0 + trow) * CIN + c0 + cpart * 16;
  ((uint4*)dst)[0] = *(const uint4*)(tmp);
  ((uint4*)dst)[1] = *(const uint4*)(tmp + 8);
}

// ---------------------------------------------------------------------------
// K1b: convert proj_w -> bf16; embed -> bf16*(-2); e_norm[k] = ||embed_k||^2
// ---------------------------------------------------------------------------
__global__ __launch_bounds__(256) void k_prep(const float* __restrict__ Wf,
                                              const float* __restrict__ Ef,
                                              unsigned short* __restrict__ Wbf,
                                              unsigned short* __restrict__ Ebf,
                                              float* __restrict__ e_norm) {
  int bid = blockIdx.x;
  if (bid < 512) {                      // W: 256*512 = 131072 elems
    int i = bid * 256 + threadIdx.x;
    Wbf[i] = f2bf(Wf[i]);
  } else if (bid < 1536) {              // E scaled by -2 (exact): 262144 elems
    int i = (bid - 512) * 256 + threadIdx.x;
    Ebf[i] = f2bf(-2.0f * Ef[i]);
  } else {                              // e_norm: 256 blocks * 4 codes (1 wave/code)
    int w = threadIdx.x >> 6, l = threadIdx.x & 63;
    int k = (bid - 1536) * 4 + w;
    const float4 v4 = ((const float4*)(Ef + (size_t)k * EF))[l];
    float s = v4.x * v4.x + v4.y * v4.y + v4.z * v4.z + v4.w * v4.w;
    for (int off = 32; off; off >>= 1) s += __shfl_down(s, off);
    if (l == 0) e_norm[k] = s;
  }
}

// ---------------------------------------------------------------------------
// K2: GEMM1: x[tok][e] = sum_c Abf[tok][c]*Wbf[e][c] + bias[e]  -> x_bf (bf16)
// block: 256 thr (4 waves), tile 64 tok x 256 e, BK=64, 8 k-stages
// LDS chunk-swizzle: phys_chunk = logical_chunk ^ (row&7) (conflict-free b128)
// ---------------------------------------------------------------------------
__global__ __launch_bounds__(256) void k_gemm1(const unsigned short* __restrict__ Abf,
                                               const unsigned short* __restrict__ Wbf,
                                               const float* __restrict__ bias,
                                               unsigned short* __restrict__ x_bf) {
  __shared__ unsigned short lds[4096 + 16384];  // as [64][64], bs [256][64]
  unsigned short* as = lds;
  unsigned short* bs = lds + 4096;
  int tid = threadIdx.x;
  int w = tid >> 6, l = tid & 63;
  int l15 = l & 15, quad = l >> 4;
  int tok0 = blockIdx.x * 64;

  f32x4 acc[4][4];
#pragma unroll
  for (int a = 0; a < 4; ++a)
#pragma unroll
    for (int b = 0; b < 4; ++b) acc[a][b] = (f32x4){0.f, 0.f, 0.f, 0.f};

  for (int ks = 0; ks < 8; ++ks) {
    int k0 = ks * 64;
#pragma unroll
    for (int i = 0; i < 2; ++i) {       // stage A: 512 chunks
      int g = i * 256 + tid;
      int row = g >> 3, pc = g & 7, lc = pc ^ (row & 7);
      GLL(Abf + (size_t)(tok0 + row) * CIN + k0 + lc * 8, as + g * 8);
    }
#pragma unroll
    for (int i = 0; i < 8; ++i) {       // stage B: 2048 chunks (all 256 e-rows)
      int g = i * 256 + tid;
      int row = g >> 3, pc = g & 7, lc = pc ^ (row & 7);
      GLL(Wbf + (size_t)row * CIN + k0 + lc * 8, bs + g * 8);
    }
    __syncthreads();
#pragma unroll
    for (int s = 0; s < 2; ++s) {
      int lcb = s * 4 + quad;
      bf16x8 af[4], bfr[4];
#pragma unroll
      for (int msub = 0; msub < 4; ++msub) {
        int row = msub * 16 + l15;
        int pc = lcb ^ (row & 7);
        af[msub] = *(const bf16x8*)(as + row * 64 + pc * 8);
      }
#pragma unroll
      for (int nsub = 0; nsub < 4; ++nsub) {
        int row = w * 64 + nsub * 16 + l15;
        int pc = lcb ^ (row & 7);
        bfr[nsub] = *(const bf16x8*)(bs + row * 64 + pc * 8);
      }
#pragma unroll
      for (int msub = 0; msub < 4; ++msub)
#pragma unroll
        for (int nsub = 0; nsub < 4; ++nsub)
          acc[msub][nsub] = __builtin_amdgcn_mfma_f32_16x16x32_bf16(af[msub], bfr[nsub],
                                                                    acc[msub][nsub], 0, 0, 0);
    }
    __syncthreads();
  }
  // epilogue: D elem (m,n): n = l&15, m = quad*4+reg (within 16x16 subtile)
#pragma unroll
  for (int nsub = 0; nsub < 4; ++nsub) {
    int col = w * 64 + nsub * 16 + l15;
    float bv = bias[col];
#pragma unroll
    for (int msub = 0; msub < 4; ++msub)
#pragma unroll
      for (int reg = 0; reg < 4; ++reg) {
        int m = msub * 16 + quad * 4 + reg;
        x_bf[(size_t)(tok0 + m) * EF + col] = f2bf(acc[msub][nsub][reg] + bv);
      }
  }
}

// ---------------------------------------------------------------------------
// K3: distances + argmin. score[t][k] = ||e_k||^2 - 2 x_t . e_k
//   (acc init = e_norm, embed pre-scaled by -2)
// block: 512 thr (8 waves), tile 256 tok x 512 codes (blockIdx.y = code half)
// waves: wy = w&3 (64-token group), wz = w>>2 (chunk parity); wave tile 64x128
// ---------------------------------------------------------------------------
__global__ __launch_bounds__(512, 2) void k_dist(const unsigned short* __restrict__ x_bf,
                                                 const unsigned short* __restrict__ Ebf,
                                                 const float* __restrict__ e_norm,
                                                 float* __restrict__ bv_out,
                                                 int* __restrict__ bi_out) {
  __shared__ unsigned short lds[32768];  // xs [256][64] (16384) + es [2][128][64] (16384)
  unsigned short* xs = lds;
  unsigned short* es = lds + 16384;
  int tid = threadIdx.x;
  int w = tid >> 6, l = tid & 63;
  int wy = w & 3, wz = w >> 2;
  int l15 = l & 15, quad = l >> 4;
  int tok0 = blockIdx.x * 256;
  int c0 = blockIdx.y * 512;

  float best_v[4][4];
  int best_i[4][4];
#pragma unroll
  for (int a = 0; a < 4; ++a)
#pragma unroll
    for (int b = 0; b < 4; ++b) { best_v[a][b] = 3.0e38f; best_i[a][b] = 0; }

  for (int j = 0; j < 2; ++j) {
    int cbase = c0 + (2 * j + wz) * 128;
    f32x4 acc[4][8];
#pragma unroll
    for (int nsub = 0; nsub < 8; ++nsub) {
      float en = e_norm[cbase + nsub * 16 + l15];
#pragma unroll
      for (int msub = 0; msub < 4; ++msub) acc[msub][nsub] = (f32x4){en, en, en, en};
    }
    for (int ks = 0; ks < 4; ++ks) {
      int k0 = ks * 64;
#pragma unroll
      for (int i = 0; i < 4; ++i) {      // stage xs: 2048 chunks
        int g = i * 512 + tid;
        int row = g >> 3, pc = g & 7, lc = pc ^ (row & 7);
        GLL(x_bf + (size_t)(tok0 + row) * EF + k0 + lc * 8, xs + g * 8);
      }
#pragma unroll
      for (int i = 0; i < 4; ++i) {      // stage es: 2048 chunks (2 z-slabs)
        int g = i * 512 + tid;
        int z = g >> 10, gg = g & 1023;
        int n = gg >> 3, pc = gg & 7, lc = pc ^ (n & 7);
        GLL(Ebf + (size_t)(c0 + (2 * j + z) * 128 + n) * EF + k0 + lc * 8, es + g * 8);
      }
      __syncthreads();
#pragma unroll
      for (int s = 0; s < 2; ++s) {
        int lcb = s * 4 + quad;
        bf16x8 af[4], bfr[8];
#pragma unroll
        for (int msub = 0; msub < 4; ++msub) {
          int row = wy * 64 + msub * 16 + l15;
          int pc = lcb ^ (row & 7);
          af[msub] = *(const bf16x8*)(xs + row * 64 + pc * 8);
        }
#pragma unroll
        for (int nsub = 0; nsub < 8; ++nsub) {
          int n = nsub * 16 + l15;
          int pc = lcb ^ (n & 7);
          bfr[nsub] = *(const bf16x8*)(es + wz * 8192 + n * 64 + pc * 8);
        }
#pragma unroll
        for (int msub = 0; msub < 4; ++msub)
#pragma unroll
          for (int nsub = 0; nsub < 8; ++nsub)
            acc[msub][nsub] = __builtin_amdgcn_mfma_f32_16x16x32_bf16(af[msub], bfr[nsub],
                                                                      acc[msub][nsub], 0, 0, 0);
      }
      __syncthreads();
    }
    // running argmin over this chunk's 128 codes
#pragma unroll
    for (int msub = 0; msub < 4; ++msub)
#pragma unroll
      for (int nsub = 0; nsub < 8; ++nsub) {
        int code = cbase + nsub * 16 + l15;
#pragma unroll
        for (int reg = 0; reg < 4; ++reg) {
          float v = acc[msub][nsub][reg];
          if (v < best_v[msub][reg]) { best_v[msub][reg] = v; best_i[msub][reg] = code; }
        }
      }
  }
  // reduce over the 16 lanes (n within subtile)
#pragma unroll
  for (int msub = 0; msub < 4; ++msub)
#pragma unroll
    for (int reg = 0; reg < 4; ++reg) {
      float v = best_v[msub][reg];
      int idx = best_i[msub][reg];
#pragma unroll
      for (int off = 8; off; off >>= 1) {
        float ov = __shfl_xor(v, off, 16);
        int oi = __shfl_xor(idx, off, 16);
        if (ov < v || (ov == v && oi < idx)) { v = ov; idx = oi; }
      }
      best_v[msub][reg] = v;
      best_i[msub][reg] = idx;
    }
  __syncthreads();                        // es reads are done; reuse es space
  float* red_v = (float*)(es);            // [2][256]
  int* red_i = (int*)(es) + 512;          // [2][256]
  if (l15 == 0) {
#pragma unroll
    for (int msub = 0; msub < 4; ++msub)
#pragma unroll
      for (int reg = 0; reg < 4; ++reg) {
        int tl = wy * 64 + msub * 16 + quad * 4 + reg;
        red_v[wz * 256 + tl] = best_v[msub][reg];
        red_i[wz * 256 + tl] = best_i[msub][reg];
      }
  }
  __syncthreads();
  if (tid < 256) {
    float v0 = red_v[tid], v1 = red_v[256 + tid];
    int i0 = red_i[tid], i1 = red_i[256 + tid];
    float v; int id;
    if (v1 < v0 || (v1 == v0 && i1 < i0)) { v = v1; id = i1; } else { v = v0; id = i0; }
    bv_out[blockIdx.y * NTOK + tok0 + tid] = v;
    bi_out[blockIdx.y * NTOK + tok0 + tid] = id;
  }
}

// ---------------------------------------------------------------------------
// K4: merge halves, gather embed rows (fp32 exact), write z_q transposed
// [B][EF][TT], accumulate SSE((z_q-x)^2) and histogram. 32 tokens/block.
// ---------------------------------------------------------------------------
__global__ __launch_bounds__(256) void k_gather(const float* __restrict__ embed,
                                                const unsigned short* __restrict__ x_bf,
                                                const float* __restrict__ bv,
                                                const int* __restrict__ bi,
                                                float* __restrict__ out,
                                                unsigned int* __restrict__ hist,
                                                float* __restrict__ sse) {
  __shared__ float zq[EF * 32];
  __shared__ int idxs[32];
  __shared__ float wred[4];
  int tid = threadIdx.x;
  int tok0 = blockIdx.x * 32;
  if (tid < 32) {
    int tok = tok0 + tid;
    float v0 = bv[tok], v1 = bv[NTOK + tok];
    int i0 = bi[tok], i1 = bi[NTOK + tok];
    int id = (v1 < v0 || (v1 == v0 && i1 < i0)) ? i1 : i0;
    idxs[tid] = id;
    atomicAdd(&hist[id], 1u);
  }
  __syncthreads();
  int w = tid >> 6, l = tid & 63;
  float local_sse = 0.f;
  for (int r = 0; r < 8; ++r) {
    int tl = r * 4 + w;
    int id = idxs[tl];
    const float* erow = embed + (size_t)id * EF;
    const unsigned short* xrow = x_bf + (size_t)(tok0 + tl) * EF;
#pragma unroll
    for (int jj = 0; jj < 4; ++jj) {
      int e = l + 64 * jj;
      float ze = erow[e];
      float xv = bf2f(xrow[e]);
      float d = ze - xv;
      local_sse += d * d;
      zq[e * 32 + ((tl + e) & 31)] = ze;   // rotate-swizzle: conflict-free both phases
    }
  }
  __syncthreads();
  int b = tok0 >> 12;
  int t0 = tok0 & 4095;
  int tloc = l & 31;
  for (int rr = 0; rr < 32; ++rr) {
    int e = rr * 8 + w * 2 + (l >> 5);
    float v = zq[e * 32 + ((tloc + e) & 31)];
    out[((size_t)(b * EF + e) << 12) + t0 + tloc] = v;
  }
  for (int off = 32; off; off >>= 1) local_sse += __shfl_down(local_sse, off);
  if (l == 0) wred[w] = local_sse;
  __syncthreads();
  if (tid == 0) atomicAdd(sse, wred[0] + wred[1] + wred[2] + wred[3]);
}

// ---------------------------------------------------------------------------
// K5: finalize scalars
// ---------------------------------------------------------------------------
__global__ __launch_bounds__(256) void k_final(const unsigned int* __restrict__ hist,
                                               const float* __restrict__ sse,
                                               float* __restrict__ out) {
  __shared__ float red[4];
  int tid = threadIdx.x;
  float local = 0.f;
  for (int i = tid; i < NE; i += 256) {
    float p = (float)hist[i] * (1.0f / 65536.0f);
    local -= p * logf(p + 1e-10f);
  }
  for (int off = 32; off; off >>= 1) local += __shfl_down(local, off);
  if ((tid & 63) == 0) red[tid >> 6] = local;
  __syncthreads();
  if (tid == 0) {
    float lp = red[0] + red[1] + red[2] + red[3];
    out[16777216] = 1.25f * sse[0] / 16777216.0f;  // vq + 0.25*commitment
    out[16777233] = lp;
  }
  if (tid < 16) out[16777217 + tid] = 6.93147180559945f * 4096.0f;  // log(1024)*4096
}

// ---------------------------------------------------------------------------
extern "C" void kernel_launch(void* const* d_in, const int* in_sizes, int n_in,
                              void* d_out, int out_size, void* d_ws, size_t ws_size,
                              hipStream_t stream) {
  const float* inputs = (const float*)d_in[0];
  const float* proj_w = (const float*)d_in[1];
  const float* proj_b = (const float*)d_in[2];
  const float* embed = (const float*)d_in[3];
  float* out = (float*)d_out;
  char* ws = (char*)d_ws;

  // workspace layout
  unsigned short* Abf  = (unsigned short*)(ws);               // 67,108,864 B
  unsigned short* x_bf = (unsigned short*)(ws + 67108864);    // 33,554,432 B
  unsigned short* Wbf  = (unsigned short*)(ws + 100663296);   //    262,144 B
  unsigned short* Ebf  = (unsigned short*)(ws + 100925440);   //    524,288 B
  float* e_norm        = (float*)(ws + 101449728);            //      4,096 B
  float* bv            = (float*)(ws + 101453824);            //    524,288 B
  int* bi              = (int*)(ws + 101978112);              //    524,288 B
  unsigned int* hist   = (unsigned int*)(ws + 102502400);     //      4,096 B
  float* sse           = (float*)(ws + 102506496);            //          4 B
  if (ws_size < 102506752) return;

  hipMemsetAsync(ws + 102502400, 0, 4352, stream);  // hist + sse

  k_transpose<<<dim3(64, 8, 16), 256, 0, stream>>>(inputs, Abf);
  k_prep<<<1792, 256, 0, stream>>>(proj_w, embed, Wbf, Ebf, e_norm);
  k_gemm1<<<1024, 256, 0, stream>>>(Abf, Wbf, proj_b, x_bf);
  k_dist<<<dim3(256, 2), 512, 0, stream>>>(x_bf, Ebf, e_norm, bv, bi);
  k_gather<<<2048, 256, 0, stream>>>(embed, x_bf, bv, bi, out, hist, sse);
  k_final<<<1, 256, 0, stream>>>(hist, sse, out);
}

// Round 2
// 316.696 us; speedup vs baseline: 1.1897x; 1.1897x over previous
//
#include <hip/hip_runtime.h>
#include <hip/hip_bf16.h>
#include <math.h>

// Problem constants
#define TT   4096     // T
#define BB   16       // B
#define NTOK 65536    // B*T
#define CIN  512      // IN_FEATS
#define EF   256      // EMBED_FEATS
#define NE   1024     // NUM_EMBED

typedef __attribute__((ext_vector_type(8))) short bf16x8;
typedef __attribute__((ext_vector_type(4))) float f32x4;

static __device__ __forceinline__ unsigned short f2bf(float f) {
  unsigned int u = __float_as_uint(f);
  u += 0x7fffu + ((u >> 16) & 1u);          // RNE
  return (unsigned short)(u >> 16);
}

// async global->LDS, 16B per lane; LDS dest is wave-uniform base + lane*16
#define GLL(gsrc, ldst) \
  __builtin_amdgcn_global_load_lds((const __attribute__((address_space(1))) void*)(gsrc), \
                                   (__attribute__((address_space(3))) void*)(ldst), 16, 0, 0)

// ---------------------------------------------------------------------------
// K0: convert proj_w -> bf16; embed -> bf16*(-2); e_norm[k] = ||embed_k||^2
// ---------------------------------------------------------------------------
__global__ __launch_bounds__(256) void k_prep(const float* __restrict__ Wf,
                                              const float* __restrict__ Ef,
                                              unsigned short* __restrict__ Wbf,
                                              unsigned short* __restrict__ Ebf,
                                              float* __restrict__ e_norm) {
  int bid = blockIdx.x;
  if (bid < 512) {                      // W: 256*512 = 131072 elems
    int i = bid * 256 + threadIdx.x;
    Wbf[i] = f2bf(Wf[i]);
  } else if (bid < 1536) {              // E scaled by -2 (exact): 262144 elems
    int i = (bid - 512) * 256 + threadIdx.x;
    Ebf[i] = f2bf(-2.0f * Ef[i]);
  } else {                              // e_norm: 256 blocks * 4 codes (1 wave/code)
    int w = threadIdx.x >> 6, l = threadIdx.x & 63;
    int k = (bid - 1536) * 4 + w;
    const float4 v4 = ((const float4*)(Ef + (size_t)k * EF))[l];
    float s = v4.x * v4.x + v4.y * v4.y + v4.z * v4.z + v4.w * v4.w;
    for (int off = 32; off; off >>= 1) s += __shfl_down(s, off);
    if (l == 0) e_norm[k] = s;
  }
}

// ---------------------------------------------------------------------------
// K1 (fused): per 64-token block:
//  phase1: x[tok][e] = sum_c in[b][c][t]*W[e][c]  (A transposed+converted in
//          registers -> swizzled LDS; W via global_load_lds)
//  phase2: x += bias -> bf16 into LDS xs[64][256]; xsq += x^2 (f32, pre-round)
//  phase3: dist[tok][code] = ||e||^2 - 2 x.e  (Ebf pre-scaled by -2, acc init
//          = e_norm); 4 chunks of 256 codes, 64 codes/wave -> acc[4][4]
//  phase4: argmin merge (lane16 shfl -> cross-wave LDS) -> bi, hist,
//          sse += sum(best_v) + sum(x^2)
// LDS 64 KB: phase1 as[64][64]@0 (8K) bs[256][64]@8K (32K);
//            phase2/3 xs[64][256]@0 (32K) es[256][64]@32K (32K)
// ---------------------------------------------------------------------------
__global__ __launch_bounds__(256, 2) void k_fused(const float* __restrict__ in,
                                                  const unsigned short* __restrict__ Wbf,
                                                  const float* __restrict__ bias,
                                                  const unsigned short* __restrict__ Ebf,
                                                  const float* __restrict__ e_norm,
                                                  int* __restrict__ bi_out,
                                                  unsigned int* __restrict__ hist,
                                                  float* __restrict__ sse) {
  __shared__ unsigned short lds[32768];
  unsigned short* as_ = lds;            // phase1 A tile [64 t][64 c]
  unsigned short* bs = lds + 4096;      // phase1 W tile [256 e][64 c]
  unsigned short* xs = lds;             // phase2/3 x tile [64 t][256 e]
  unsigned short* es = lds + 16384;     // phase3 embed tile [256 code][64 e]

  int tid = threadIdx.x;
  int w = tid >> 6, l = tid & 63;
  int l15 = l & 15, quad = l >> 4;
  int tok0 = blockIdx.x * 64;
  int bidx = tok0 >> 12;
  int tg0 = tok0 & 4095;
  const float* src = in + (size_t)bidx * CIN * TT + tg0;

  // ------------------ phase 1: projection GEMM ------------------
  f32x4 acc[4][4];
#pragma unroll
  for (int a = 0; a < 4; ++a)
#pragma unroll
    for (int b = 0; b < 4; ++b) acc[a][b] = (f32x4){0.f, 0.f, 0.f, 0.f};

  for (int ks = 0; ks < 8; ++ks) {
    int k0 = ks * 64;
    // A: transposed loads (lane over t, 16 c's per thread), coalesced dwords
    float v[16];
    const float* s0 = src + (size_t)(k0 + w * 16) * TT + l;
#pragma unroll
    for (int i = 0; i < 16; ++i) v[i] = s0[(size_t)i * TT];
    // W: async global->LDS (2048 16B chunks)
#pragma unroll
    for (int i = 0; i < 8; ++i) {
      int g = i * 256 + tid;
      int row = g >> 3, pc = g & 7, lc = pc ^ (row & 7);
      GLL(Wbf + (size_t)row * CIN + k0 + lc * 8, bs + g * 8);
    }
    // pack+write A (swizzled chunk = c8 ^ (t&7); b128 writes cover all banks)
#pragma unroll
    for (int cc = 0; cc < 2; ++cc) {
      alignas(16) unsigned short tmp[8];
#pragma unroll
      for (int j = 0; j < 8; ++j) tmp[j] = f2bf(v[cc * 8 + j]);
      int c8 = w * 2 + cc;
      int pc = c8 ^ (l & 7);
      *(bf16x8*)(as_ + l * 64 + pc * 8) = *(const bf16x8*)tmp;
    }
    __syncthreads();
#pragma unroll
    for (int s = 0; s < 2; ++s) {
      int lcb = s * 4 + quad;
      bf16x8 af[4], bfr[4];
#pragma unroll
      for (int msub = 0; msub < 4; ++msub) {
        int row = msub * 16 + l15;
        int pc = lcb ^ (row & 7);
        af[msub] = *(const bf16x8*)(as_ + row * 64 + pc * 8);
      }
#pragma unroll
      for (int nsub = 0; nsub < 4; ++nsub) {
        int row = w * 64 + nsub * 16 + l15;
        int pc = lcb ^ (row & 7);
        bfr[nsub] = *(const bf16x8*)(bs + row * 64 + pc * 8);
      }
#pragma unroll
      for (int msub = 0; msub < 4; ++msub)
#pragma unroll
        for (int nsub = 0; nsub < 4; ++nsub)
          acc[msub][nsub] = __builtin_amdgcn_mfma_f32_16x16x32_bf16(af[msub], bfr[nsub],
                                                                    acc[msub][nsub], 0, 0, 0);
    }
    __syncthreads();
  }

  // ------------------ phase 2: bias + x -> LDS xs, xsq ------------------
  float xsq = 0.f;
  float bv4[4];
#pragma unroll
  for (int nsub = 0; nsub < 4; ++nsub) bv4[nsub] = bias[w * 64 + nsub * 16 + l15];
#pragma unroll
  for (int msub = 0; msub < 4; ++msub)
#pragma unroll
    for (int nsub = 0; nsub < 4; ++nsub)
#pragma unroll
      for (int reg = 0; reg < 4; ++reg) {
        int m = msub * 16 + quad * 4 + reg;
        int e = w * 64 + nsub * 16 + l15;
        float x = acc[msub][nsub][reg] + bv4[nsub];
        xsq += x * x;
        int cx = e >> 3, pcx = cx ^ (m & 31);
        xs[m * 256 + pcx * 8 + (e & 7)] = f2bf(x);
      }
  __syncthreads();

  // ------------------ phase 3: distances + running argmin ------------------
  float best_v[4][4];
  int best_i[4][4];
#pragma unroll
  for (int a = 0; a < 4; ++a)
#pragma unroll
    for (int b = 0; b < 4; ++b) { best_v[a][b] = 3.0e38f; best_i[a][b] = 0; }

  for (int chunk = 0; chunk < 4; ++chunk) {
    int c0 = chunk * 256;
    f32x4 dacc[4][4];
#pragma unroll
    for (int nsub = 0; nsub < 4; ++nsub) {
      float en = e_norm[c0 + w * 64 + nsub * 16 + l15];
#pragma unroll
      for (int msub = 0; msub < 4; ++msub) dacc[msub][nsub] = (f32x4){en, en, en, en};
    }
    for (int ks = 0; ks < 4; ++ks) {
      int k0 = ks * 64;
#pragma unroll
      for (int i = 0; i < 8; ++i) {
        int g = i * 256 + tid;
        int row = g >> 3, pc = g & 7, lc = pc ^ (row & 7);
        GLL(Ebf + (size_t)(c0 + row) * EF + k0 + lc * 8, es + g * 8);
      }
      __syncthreads();
#pragma unroll
      for (int s = 0; s < 2; ++s) {
        bf16x8 af[4], bfr[4];
        int cx = ks * 8 + s * 4 + quad;   // k-chunk within xs row (0..31)
#pragma unroll
        for (int msub = 0; msub < 4; ++msub) {
          int row = msub * 16 + l15;
          int pcx = cx ^ (row & 31);
          af[msub] = *(const bf16x8*)(xs + row * 256 + pcx * 8);
        }
        int ck = s * 4 + quad;            // k-chunk within es row (0..7)
#pragma unroll
        for (int nsub = 0; nsub < 4; ++nsub) {
          int row = w * 64 + nsub * 16 + l15;
          int pc = ck ^ (row & 7);
          bfr[nsub] = *(const bf16x8*)(es + row * 64 + pc * 8);
        }
#pragma unroll
        for (int msub = 0; msub < 4; ++msub)
#pragma unroll
          for (int nsub = 0; nsub < 4; ++nsub)
            dacc[msub][nsub] = __builtin_amdgcn_mfma_f32_16x16x32_bf16(af[msub], bfr[nsub],
                                                                       dacc[msub][nsub], 0, 0, 0);
      }
      __syncthreads();
    }
#pragma unroll
    for (int msub = 0; msub < 4; ++msub)
#pragma unroll
      for (int nsub = 0; nsub < 4; ++nsub) {
        int code = c0 + w * 64 + nsub * 16 + l15;
#pragma unroll
        for (int reg = 0; reg < 4; ++reg) {
          float v = dacc[msub][nsub][reg];
          if (v < best_v[msub][reg]) { best_v[msub][reg] = v; best_i[msub][reg] = code; }
        }
      }
  }

  // ------------------ phase 4: argmin merge, outputs ------------------
#pragma unroll
  for (int msub = 0; msub < 4; ++msub)
#pragma unroll
    for (int reg = 0; reg < 4; ++reg) {
      float v = best_v[msub][reg];
      int idx = best_i[msub][reg];
#pragma unroll
      for (int off = 8; off; off >>= 1) {
        float ov = __shfl_xor(v, off, 16);
        int oi = __shfl_xor(idx, off, 16);
        if (ov < v || (ov == v && oi < idx)) { v = ov; idx = oi; }
      }
      best_v[msub][reg] = v;
      best_i[msub][reg] = idx;
    }
  float* red_v = (float*)es;         // [4][64]
  int* red_i = (int*)(es) + 256;     // [4][64]
  float* xred = (float*)(es) + 512;  // [4]
  if (l15 == 0) {
#pragma unroll
    for (int msub = 0; msub < 4; ++msub)
#pragma unroll
      for (int reg = 0; reg < 4; ++reg) {
        int m = msub * 16 + quad * 4 + reg;
        red_v[w * 64 + m] = best_v[msub][reg];
        red_i[w * 64 + m] = best_i[msub][reg];
      }
  }
  for (int off = 32; off; off >>= 1) xsq += __shfl_down(xsq, off);
  if (l == 0) xred[w] = xsq;
  __syncthreads();
  if (tid < 64) {
    float v = red_v[tid];
    int idx = red_i[tid];
#pragma unroll
    for (int wj = 1; wj < 4; ++wj) {
      float ov = red_v[wj * 64 + tid];
      int oi = red_i[wj * 64 + tid];
      if (ov < v || (ov == v && oi < idx)) { v = ov; idx = oi; }
    }
    bi_out[tok0 + tid] = idx;
    atomicAdd(&hist[idx], 1u);
    float sv = v;
    for (int off = 32; off; off >>= 1) sv += __shfl_down(sv, off);
    if (tid == 0) atomicAdd(sse, sv + xred[0] + xred[1] + xred[2] + xred[3]);
  }
}

// ---------------------------------------------------------------------------
// K2: gather embed rows (fp32 exact) by final index, write z_q transposed
// [B][EF][TT]. 32 tokens/block, rotate-swizzled LDS transpose.
// ---------------------------------------------------------------------------
__global__ __launch_bounds__(256) void k_gather(const float* __restrict__ embed,
                                                const int* __restrict__ bi,
                                                float* __restrict__ out) {
  __shared__ float zq[EF * 32];
  __shared__ int idxs[32];
  int tid = threadIdx.x;
  int tok0 = blockIdx.x * 32;
  if (tid < 32) idxs[tid] = bi[tok0 + tid];
  __syncthreads();
  int w = tid >> 6, l = tid & 63;
  for (int r = 0; r < 8; ++r) {
    int tl = r * 4 + w;
    const float* erow = embed + (size_t)idxs[tl] * EF;
#pragma unroll
    for (int jj = 0; jj < 4; ++jj) {
      int e = l + 64 * jj;
      zq[e * 32 + ((tl + e) & 31)] = erow[e];   // rotate-swizzle: conflict-free
    }
  }
  __syncthreads();
  int b = tok0 >> 12;
  int t0 = tok0 & 4095;
  int tloc = l & 31;
  for (int rr = 0; rr < 32; ++rr) {
    int e = rr * 8 + w * 2 + (l >> 5);
    out[((size_t)(b * EF + e) << 12) + t0 + tloc] = zq[e * 32 + ((tloc + e) & 31)];
  }
}

// ---------------------------------------------------------------------------
// K3: finalize scalars
// ---------------------------------------------------------------------------
__global__ __launch_bounds__(256) void k_final(const unsigned int* __restrict__ hist,
                                               const float* __restrict__ sse,
                                               float* __restrict__ out) {
  __shared__ float red[4];
  int tid = threadIdx.x;
  float local = 0.f;
  for (int i = tid; i < NE; i += 256) {
    float p = (float)hist[i] * (1.0f / 65536.0f);
    local -= p * logf(p + 1e-10f);
  }
  for (int off = 32; off; off >>= 1) local += __shfl_down(local, off);
  if ((tid & 63) == 0) red[tid >> 6] = local;
  __syncthreads();
  if (tid == 0) {
    float lp = red[0] + red[1] + red[2] + red[3];
    out[16777216] = 1.25f * sse[0] / 16777216.0f;  // vq + 0.25*commitment
    out[16777233] = lp;
  }
  if (tid < 16) out[16777217 + tid] = 6.93147180559945f * 4096.0f;  // log(1024)*4096
}

// ---------------------------------------------------------------------------
extern "C" void kernel_launch(void* const* d_in, const int* in_sizes, int n_in,
                              void* d_out, int out_size, void* d_ws, size_t ws_size,
                              hipStream_t stream) {
  const float* inputs = (const float*)d_in[0];
  const float* proj_w = (const float*)d_in[1];
  const float* proj_b = (const float*)d_in[2];
  const float* embed = (const float*)d_in[3];
  float* out = (float*)d_out;
  char* ws = (char*)d_ws;

  // workspace layout
  unsigned short* Wbf  = (unsigned short*)(ws);            //   262,144 B
  unsigned short* Ebf  = (unsigned short*)(ws + 262144);   //   524,288 B
  float* e_norm        = (float*)(ws + 786432);            //     4,096 B
  int* bi              = (int*)(ws + 790528);              //   262,144 B
  unsigned int* hist   = (unsigned int*)(ws + 1052672);    //     4,096 B
  float* sse           = (float*)(ws + 1056768);           //         4 B
  if (ws_size < 1056772) return;

  hipMemsetAsync(ws + 1052672, 0, 4100, stream);  // hist + sse

  k_prep<<<1792, 256, 0, stream>>>(proj_w, embed, Wbf, Ebf, e_norm);
  k_fused<<<1024, 256, 0, stream>>>(inputs, Wbf, proj_b, Ebf, e_norm, bi, hist, sse);
  k_gather<<<2048, 256, 0, stream>>>(embed, bi, out);
  k_final<<<1, 256, 0, stream>>>(hist, sse, out);
}